// Round 1
// baseline (43.645 us; speedup 1.0000x reference)
//
#include <hip/hip_runtime.h>

// Problem constants (from reference)
#define BB 8
#define LL 8192
#define DD 1024
#define NN 256
#define PP 32
#define D4 (DD / 4)   // 256 float4 per row

__global__ __launch_bounds__(256) void page_encoder_kernel(
    const float* __restrict__ hs,        // [B, L, D]
    const int*   __restrict__ page_idx,  // [B, N, P]  (-1 = invalid)
    const int*   __restrict__ input_ids, // [B, L]
    const float* __restrict__ tlw,       // [B, L]
    const float* __restrict__ idf,       // [V]
    float*       __restrict__ out)       // [B, N, D]
{
    const int bn  = blockIdx.x;          // 0 .. B*N-1
    const int b   = bn >> 8;             // N = 256
    const int tid = threadIdx.x;         // 0 .. 255 -> float4 lane

    __shared__ int   s_idx[PP];
    __shared__ float s_w[PP];

    // First 32 threads stage per-slot index + effective weight.
    if (tid < PP) {
        int idx = page_idx[(size_t)bn * PP + tid];
        float w = 0.0f;
        if (idx >= 0) {
            const int off = b * LL + idx;
            w = idf[input_ids[off]] * tlw[off];
        }
        s_idx[tid] = idx;
        s_w[tid]   = w;
    }
    __syncthreads();

    const float4* hsb = reinterpret_cast<const float4*>(hs) + (size_t)b * LL * D4;

    float4 sum  = make_float4(0.f, 0.f, 0.f, 0.f);
    float4 wsum = make_float4(0.f, 0.f, 0.f, 0.f);
    float4 vmax = make_float4(-10000.f, -10000.f, -10000.f, -10000.f);
    float  w_total = 0.f;
    int    cnt     = 0;

    #pragma unroll
    for (int p = 0; p < PP; ++p) {
        const int idx = s_idx[p];        // wave-uniform
        if (idx >= 0) {
            const float4 v = hsb[(size_t)idx * D4 + tid];
            const float  w = s_w[p];
            sum.x += v.x;  sum.y += v.y;  sum.z += v.z;  sum.w += v.w;
            wsum.x = fmaf(w, v.x, wsum.x);
            wsum.y = fmaf(w, v.y, wsum.y);
            wsum.z = fmaf(w, v.z, wsum.z);
            wsum.w = fmaf(w, v.w, wsum.w);
            vmax.x = fmaxf(vmax.x, v.x);
            vmax.y = fmaxf(vmax.y, v.y);
            vmax.z = fmaxf(vmax.z, v.z);
            vmax.w = fmaxf(vmax.w, v.w);
            w_total += w;
            cnt++;
        }
    }

    // low = w_sum < 1e-4 dominates the w_sum_safe(1e-6) branch:
    // if w_total >= 1e-4 then w_sum_safe == w_total.
    float4 mean;
    if (w_total < 1e-4f) {
        const float inv = 1.0f / fmaxf((float)cnt, 1.0f);
        mean.x = sum.x * inv; mean.y = sum.y * inv;
        mean.z = sum.z * inv; mean.w = sum.w * inv;
    } else {
        const float inv = 1.0f / w_total;
        mean.x = wsum.x * inv; mean.y = wsum.y * inv;
        mean.z = wsum.z * inv; mean.w = wsum.w * inv;
    }

    float4 o;
    o.x = 0.7f * mean.x + 0.3f * vmax.x;
    o.y = 0.7f * mean.y + 0.3f * vmax.y;
    o.z = 0.7f * mean.z + 0.3f * vmax.z;
    o.w = 0.7f * mean.w + 0.3f * vmax.w;

    reinterpret_cast<float4*>(out)[(size_t)bn * D4 + tid] = o;
}

extern "C" void kernel_launch(void* const* d_in, const int* in_sizes, int n_in,
                              void* d_out, int out_size, void* d_ws, size_t ws_size,
                              hipStream_t stream) {
    const float* hs        = (const float*)d_in[0];  // hidden_states [B,L,D] f32
    const int*   page_idx  = (const int*)  d_in[1];  // page_indices  [B,N,P]
    // d_in[2] = page_valid — unused: page_valid == (page_indices >= 0) by construction
    const int*   input_ids = (const int*)  d_in[3];  // input_ids     [B,L]
    const float* tlw       = (const float*)d_in[4];  // token_level_weights [B,L]
    const float* idf       = (const float*)d_in[5];  // idf_weights   [V]
    float*       out       = (float*)      d_out;    // [B,N,D] f32

    page_encoder_kernel<<<BB * NN, 256, 0, stream>>>(hs, page_idx, input_ids, tlw, idf, out);
}

// Round 2
// 41.745 us; speedup vs baseline: 1.0455x; 1.0455x over previous
//
#include <hip/hip_runtime.h>

// Problem constants (from reference)
#define BB 8
#define LL 8192
#define DD 1024
#define NN 256
#define PP 32
#define D4 (DD / 4)   // 256 float4 per row

__global__ __launch_bounds__(256) void page_encoder_kernel(
    const float* __restrict__ hs,        // [B, L, D]
    const int*   __restrict__ page_idx,  // [B, N, P]  (-1 = invalid)
    const int*   __restrict__ input_ids, // [B, L]
    const float* __restrict__ tlw,       // [B, L]
    const float* __restrict__ idf,       // [V]
    float*       __restrict__ out)       // [B, N, D]
{
    const int bn  = blockIdx.x;          // 0 .. B*N-1
    const int b   = bn >> 8;             // N = 256
    const int tid = threadIdx.x;         // 0 .. 255 -> float4 lane

    __shared__ int   s_off[PP];          // clamped row offset in float4 units
    __shared__ float s_w[PP];            // effective weight (0 if invalid)
    __shared__ float s_v[PP];            // 1.0 valid / 0.0 invalid

    if (tid < PP) {
        const int idx   = page_idx[(size_t)bn * PP + tid];
        const int valid = idx >= 0;
        const int idxc  = valid ? idx : 0;
        float w = 0.0f;
        if (valid) {
            const int off = b * LL + idxc;
            w = idf[input_ids[off]] * tlw[off];
        }
        s_off[tid] = idxc * D4;
        s_w[tid]   = w;
        s_v[tid]   = valid ? 1.0f : 0.0f;
    }
    __syncthreads();

    const float4* hsb = reinterpret_cast<const float4*>(hs) + (size_t)b * LL * D4;

    float4 sum  = make_float4(0.f, 0.f, 0.f, 0.f);
    float4 wsum = make_float4(0.f, 0.f, 0.f, 0.f);
    float4 vmax = make_float4(-10000.f, -10000.f, -10000.f, -10000.f);
    float  w_total = 0.f;
    float  cnt     = 0.f;

    // 4 groups x 8 unconditional loads: >=8 outstanding loads per wave,
    // no branches in the hot loop. Invalid slots read row 0 (L1-hit),
    // and are neutralized arithmetically (w=0, select for max, s_v for cnt).
    #pragma unroll
    for (int g = 0; g < PP / 8; ++g) {
        float4 v[8];
        #pragma unroll
        for (int i = 0; i < 8; ++i) {
            v[i] = hsb[(size_t)s_off[g * 8 + i] + tid];
        }
        #pragma unroll
        for (int i = 0; i < 8; ++i) {
            const int   p  = g * 8 + i;
            const float w  = s_w[p];
            const float vl = s_v[p];
            sum.x += vl * v[i].x;  sum.y += vl * v[i].y;
            sum.z += vl * v[i].z;  sum.w += vl * v[i].w;
            wsum.x = fmaf(w, v[i].x, wsum.x);
            wsum.y = fmaf(w, v[i].y, wsum.y);
            wsum.z = fmaf(w, v[i].z, wsum.z);
            wsum.w = fmaf(w, v[i].w, wsum.w);
            const bool val = vl != 0.0f;
            vmax.x = fmaxf(vmax.x, val ? v[i].x : -10000.f);
            vmax.y = fmaxf(vmax.y, val ? v[i].y : -10000.f);
            vmax.z = fmaxf(vmax.z, val ? v[i].z : -10000.f);
            vmax.w = fmaxf(vmax.w, val ? v[i].w : -10000.f);
            w_total += w;
            cnt     += vl;
        }
    }

    // low = (w_sum < 1e-4) dominates the 1e-6 safe-divide branch.
    float4 mean;
    if (w_total < 1e-4f) {
        const float inv = 1.0f / fmaxf(cnt, 1.0f);
        mean.x = sum.x * inv; mean.y = sum.y * inv;
        mean.z = sum.z * inv; mean.w = sum.w * inv;
    } else {
        const float inv = 1.0f / w_total;
        mean.x = wsum.x * inv; mean.y = wsum.y * inv;
        mean.z = wsum.z * inv; mean.w = wsum.w * inv;
    }

    float4 o;
    o.x = 0.7f * mean.x + 0.3f * vmax.x;
    o.y = 0.7f * mean.y + 0.3f * vmax.y;
    o.z = 0.7f * mean.z + 0.3f * vmax.z;
    o.w = 0.7f * mean.w + 0.3f * vmax.w;

    reinterpret_cast<float4*>(out)[(size_t)bn * D4 + tid] = o;
}

extern "C" void kernel_launch(void* const* d_in, const int* in_sizes, int n_in,
                              void* d_out, int out_size, void* d_ws, size_t ws_size,
                              hipStream_t stream) {
    const float* hs        = (const float*)d_in[0];  // hidden_states [B,L,D] f32
    const int*   page_idx  = (const int*)  d_in[1];  // page_indices  [B,N,P]
    // d_in[2] = page_valid — unused: page_valid == (page_indices >= 0) by construction
    const int*   input_ids = (const int*)  d_in[3];  // input_ids     [B,L]
    const float* tlw       = (const float*)d_in[4];  // token_level_weights [B,L]
    const float* idf       = (const float*)d_in[5];  // idf_weights   [V]
    float*       out       = (float*)      d_out;    // [B,N,D] f32

    page_encoder_kernel<<<BB * NN, 256, 0, stream>>>(hs, page_idx, input_ids, tlw, idf, out);
}